// Round 1
// baseline (24358.305 us; speedup 1.0000x reference)
//
#include <hip/hip_runtime.h>
#include <hip/hip_bf16.h>

// TrajectoryDecoder: L=3 GRU (H=512) over T=64 steps, B=2048.
// Round 1: fp32 correctness anchor with full orchestration.
//   per step: gh0 -> EW0(gi0 inline,K=2) -> {gi1,gh1} -> EW1 -> {gi2,gh2} -> EW2
//             -> MLP1(relu) -> MLP2+pos+traj   (8 launches/step, graph-captured)
// Round 2 plan: swap gemm128 core to bf16 mfma_f32_16x16x32_bf16, same orchestration.

#define L_LAYERS 3
#define H 512
#define T_STEPS 64
#define LAT 128
#define COND 128
#define BATCH 2048
#define H3 1536
#define D_IN 256

struct GemmDesc {
    const float* A;    // M x K, row stride lda (K-contiguous)
    const float* W;    // (N x K) K-major if !W_NMAJOR, else (K x N) N-major
    float* C;          // M x N, row stride ldc
    const float* bias; // length N or nullptr
};

// C = A @ W^T (or A @ W if W_NMAJOR). BM=BN=128, BK=16, 256 threads, 8x8 microtile.
template <bool W_NMAJOR, bool RELU>
__global__ __launch_bounds__(256) void gemm128(GemmDesc d0, GemmDesc d1, int N,
                                               int K, int lda, int ldc) {
    GemmDesc d = blockIdx.z ? d1 : d0;
    __shared__ float As[16][128 + 4];  // k-outer so microtile reads are float4
    __shared__ float Ws[16][128 + 4];
    const int tid = threadIdx.x;
    const int tx = tid & 15, ty = tid >> 4;
    const int brow = blockIdx.y * 128;
    const int bcol = blockIdx.x * 128;

    float acc[8][8];
#pragma unroll
    for (int i = 0; i < 8; ++i)
#pragma unroll
        for (int j = 0; j < 8; ++j) acc[i][j] = 0.f;

    for (int k0 = 0; k0 < K; k0 += 16) {
        // stage A: 128 rows x 16 k = 2048 floats; 256 thr x 2 x float4
#pragma unroll
        for (int i = 0; i < 2; ++i) {
            int s = tid + 256 * i;
            int r = s >> 2;
            int c4 = (s & 3) * 4;
            float4 v = *(const float4*)(d.A + (size_t)(brow + r) * lda + k0 + c4);
            As[c4 + 0][r] = v.x;
            As[c4 + 1][r] = v.y;
            As[c4 + 2][r] = v.z;
            As[c4 + 3][r] = v.w;
        }
        if (!W_NMAJOR) {
#pragma unroll
            for (int i = 0; i < 2; ++i) {
                int s = tid + 256 * i;
                int r = s >> 2;  // n index
                int c4 = (s & 3) * 4;
                float4 v = *(const float4*)(d.W + (size_t)(bcol + r) * K + k0 + c4);
                Ws[c4 + 0][r] = v.x;
                Ws[c4 + 1][r] = v.y;
                Ws[c4 + 2][r] = v.z;
                Ws[c4 + 3][r] = v.w;
            }
        } else {
            // W is (K x N) N-major: contiguous in n
#pragma unroll
            for (int i = 0; i < 2; ++i) {
                int s = tid + 256 * i;
                int kk = s >> 5;
                int n4 = (s & 31) * 4;
                float4 v = *(const float4*)(d.W + (size_t)(k0 + kk) * N + bcol + n4);
                *(float4*)&Ws[kk][n4] = v;
            }
        }
        __syncthreads();
#pragma unroll
        for (int kk = 0; kk < 16; ++kk) {
            float a[8], w[8];
            *(float4*)&a[0] = *(const float4*)&As[kk][ty * 8];
            *(float4*)&a[4] = *(const float4*)&As[kk][ty * 8 + 4];
            *(float4*)&w[0] = *(const float4*)&Ws[kk][tx * 8];
            *(float4*)&w[4] = *(const float4*)&Ws[kk][tx * 8 + 4];
#pragma unroll
            for (int i = 0; i < 8; ++i) {
#pragma unroll
                for (int j = 0; j < 8; ++j) acc[i][j] += a[i] * w[j];
            }
        }
        __syncthreads();
    }
#pragma unroll
    for (int i = 0; i < 8; ++i) {
        int row = brow + ty * 8 + i;
#pragma unroll
        for (int j = 0; j < 8; ++j) {
            int col = bcol + tx * 8 + j;
            float v = acc[i][j];
            if (d.bias) v += d.bias[col];
            if (RELU) v = fmaxf(v, 0.f);
            d.C[(size_t)row * ldc + col] = v;
        }
    }
}

__global__ __launch_bounds__(256) void build_combined(const float* z, const float* cond,
                                                      float* combined, float* pos) {
    int idx = blockIdx.x * 256 + threadIdx.x;
    int b = idx >> 8, k = idx & 255;
    combined[idx] = (k < LAT) ? z[b * LAT + k] : cond[b * COND + (k - LAT)];
    if (idx < BATCH * 2) pos[idx] = 0.f;
}

__device__ inline float sigmoidf_(float x) { return 1.f / (1.f + expf(-x)); }

// layer 0: gi computed inline from pos (K=2)
__global__ __launch_bounds__(256) void ew_layer0(const float* gh, const float* pos,
                                                 const float* W_ih0, const float* b_ih0,
                                                 const float* b_hh0, float* h) {
    int idx = blockIdx.x * 256 + threadIdx.x;  // BATCH*H
    int b = idx >> 9, j = idx & 511;
    float px = pos[b * 2 + 0], py = pos[b * 2 + 1];
    float gi_r = px * W_ih0[j * 2 + 0] + py * W_ih0[j * 2 + 1] + b_ih0[j];
    float gi_z = px * W_ih0[(512 + j) * 2 + 0] + py * W_ih0[(512 + j) * 2 + 1] + b_ih0[512 + j];
    float gi_n = px * W_ih0[(1024 + j) * 2 + 0] + py * W_ih0[(1024 + j) * 2 + 1] + b_ih0[1024 + j];
    size_t rb = (size_t)b * H3;
    float hr = gh[rb + j] + b_hh0[j];
    float hz = gh[rb + 512 + j] + b_hh0[512 + j];
    float hn = gh[rb + 1024 + j] + b_hh0[1024 + j];
    float r = sigmoidf_(gi_r + hr);
    float zg = sigmoidf_(gi_z + hz);
    float n = tanhf(gi_n + r * hn);
    float hp = h[rb + j];  // layer0 occupies cols [0,512)
    h[rb + j] = (1.f - zg) * n + zg * hp;
}

// layers 1,2: gi/gh precomputed (B x H3); h col block [colOff, colOff+512)
__global__ __launch_bounds__(256) void ew_gruL(const float* gi, const float* gh,
                                               const float* b_ihl, const float* b_hhl,
                                               float* h, int colOff) {
    int idx = blockIdx.x * 256 + threadIdx.x;
    int b = idx >> 9, j = idx & 511;
    size_t rb = (size_t)b * H3;
    float ir = gi[rb + j] + b_ihl[j];
    float iz = gi[rb + 512 + j] + b_ihl[512 + j];
    float inn = gi[rb + 1024 + j] + b_ihl[1024 + j];
    float hr = gh[rb + j] + b_hhl[j];
    float hz = gh[rb + 512 + j] + b_hhl[512 + j];
    float hn = gh[rb + 1024 + j] + b_hhl[1024 + j];
    float r = sigmoidf_(ir + hr);
    float zg = sigmoidf_(iz + hz);
    float n = tanhf(inn + r * hn);
    float hp = h[rb + colOff + j];
    h[rb + colOff + j] = (1.f - zg) * n + zg * hp;
}

// delta = hid @ W2[t] + b2[t]; pos += delta; traj[b,t,:] = pos
__global__ __launch_bounds__(256) void mlp2_pos(const float* hid, const float* W2t,
                                                const float* b2t, float* pos, float* out,
                                                int t) {
    int b = blockIdx.x * 4 + (threadIdx.x >> 6);
    int lane = threadIdx.x & 63;
    const float* hr = hid + (size_t)b * H;
    float a0 = 0.f, a1 = 0.f;
    for (int k = lane; k < H; k += 64) {
        float x = hr[k];
        a0 += x * W2t[k * 2 + 0];
        a1 += x * W2t[k * 2 + 1];
    }
#pragma unroll
    for (int off = 32; off; off >>= 1) {
        a0 += __shfl_down(a0, off);
        a1 += __shfl_down(a1, off);
    }
    if (lane == 0) {
        float p0 = pos[b * 2 + 0] + a0 + b2t[0];
        float p1 = pos[b * 2 + 1] + a1 + b2t[1];
        pos[b * 2 + 0] = p0;
        pos[b * 2 + 1] = p1;
        out[((size_t)b * T_STEPS + t) * 2 + 0] = p0;
        out[((size_t)b * T_STEPS + t) * 2 + 1] = p1;
    }
}

extern "C" void kernel_launch(void* const* d_in, const int* in_sizes, int n_in,
                              void* d_out, int out_size, void* d_ws, size_t ws_size,
                              hipStream_t stream) {
    const float* z = (const float*)d_in[0];
    const float* cond = (const float*)d_in[1];
    const float* hp_W = (const float*)d_in[2];
    const float* hp_b = (const float*)d_in[3];
    const float* W_ih0 = (const float*)d_in[4];
    const float* W_ihr = (const float*)d_in[5];
    const float* W_hh = (const float*)d_in[6];
    const float* b_ih = (const float*)d_in[7];
    const float* b_hh = (const float*)d_in[8];
    const float* W1 = (const float*)d_in[9];
    const float* b1 = (const float*)d_in[10];
    const float* W2 = (const float*)d_in[11];
    const float* b2 = (const float*)d_in[12];
    float* out = (float*)d_out;

    float* ws = (float*)d_ws;
    float* combined = ws; ws += (size_t)BATCH * D_IN;
    float* h = ws;        ws += (size_t)BATCH * H3;   // layer l at cols [l*512,(l+1)*512)
    float* ghA = ws;      ws += (size_t)BATCH * H3;
    float* ghB = ws;      ws += (size_t)BATCH * H3;
    float* gi = ws;       ws += (size_t)BATCH * H3;
    float* hid = ws;      ws += (size_t)BATCH * H;
    float* pos = ws;      ws += (size_t)BATCH * 2;

    build_combined<<<dim3((BATCH * D_IN) / 256), dim3(256), 0, stream>>>(z, cond, combined, pos);

    {   // h0 init: combined @ hp_W^T + hp_b
        GemmDesc di{combined, hp_W, h, hp_b};
        gemm128<false, false><<<dim3(H3 / 128, BATCH / 128, 1), dim3(256), 0, stream>>>(
            di, di, H3, D_IN, D_IN, H3);
    }

    dim3 ewGrid((BATCH * H) / 256);
    for (int t = 0; t < T_STEPS; ++t) {
        {   // gh0 = h0 @ W_hh[0]^T
            GemmDesc g0{h, W_hh, ghA, nullptr};
            gemm128<false, false><<<dim3(H3 / 128, BATCH / 128, 1), dim3(256), 0, stream>>>(
                g0, g0, H3, H, H3, H3);
        }
        ew_layer0<<<ewGrid, dim3(256), 0, stream>>>(ghA, pos, W_ih0, b_ih, b_hh, h);
        {   // gi1 = h0(t) @ W_ihr[0]^T ; gh1 = h1(t-1) @ W_hh[1]^T
            GemmDesc g1{h, W_ihr, gi, nullptr};
            GemmDesc g2{h + H, W_hh + (size_t)H3 * H, ghB, nullptr};
            gemm128<false, false><<<dim3(H3 / 128, BATCH / 128, 2), dim3(256), 0, stream>>>(
                g1, g2, H3, H, H3, H3);
        }
        ew_gruL<<<ewGrid, dim3(256), 0, stream>>>(gi, ghB, b_ih + H3, b_hh + H3, h, H);
        {   // gi2 = h1(t) @ W_ihr[1]^T ; gh2 = h2(t-1) @ W_hh[2]^T
            GemmDesc g3{h + H, W_ihr + (size_t)H3 * H, gi, nullptr};
            GemmDesc g4{h + 2 * H, W_hh + (size_t)2 * H3 * H, ghB, nullptr};
            gemm128<false, false><<<dim3(H3 / 128, BATCH / 128, 2), dim3(256), 0, stream>>>(
                g3, g4, H3, H, H3, H3);
        }
        ew_gruL<<<ewGrid, dim3(256), 0, stream>>>(gi, ghB, b_ih + 2 * H3, b_hh + 2 * H3, h, 2 * H);
        {   // hid = relu(h2(t) @ W1[t] + b1[t])   (W1 is K x N, N-major)
            GemmDesc g5{h + 2 * H, W1 + (size_t)t * H * H, hid, b1 + (size_t)t * H};
            gemm128<true, true><<<dim3(H / 128, BATCH / 128, 1), dim3(256), 0, stream>>>(
                g5, g5, H, H, H3, H);
        }
        mlp2_pos<<<dim3(BATCH / 4), dim3(256), 0, stream>>>(
            hid, W2 + (size_t)t * H * 2, b2 + t * 2, pos, out, t);
    }
}

// Round 2
// 7801.720 us; speedup vs baseline: 3.1222x; 3.1222x over previous
//
#include <hip/hip_runtime.h>
#include <hip/hip_bf16.h>

// TrajectoryDecoder: L=3 GRU (H=512) over T=64 steps, B=2048.
// Round 2: bf16 MFMA GEMM core (16x16x32), same verified orchestration as R1.
//   pre: convert weights to bf16 (flat) + transpose W1 to K-major.
//   per step: gh0 -> EW0 -> {gi1,gh1} -> EW1 -> {gi2,gh2} -> EW2 -> MLP1 -> MLP2+pos
// h state and elementwise recurrence stay fp32.

#define L_LAYERS 3
#define H 512
#define T_STEPS 64
#define LAT 128
#define COND 128
#define BATCH 2048
#define H3 1536
#define D_IN 256

typedef __bf16 bf16x8 __attribute__((ext_vector_type(8)));
typedef float f32x4 __attribute__((ext_vector_type(4)));
typedef unsigned short ushort8v __attribute__((ext_vector_type(8)));

__device__ inline unsigned short f2bf(float f) {
    union { float f; unsigned int u; } v{f};
    unsigned int r = v.u + 0x7fffu + ((v.u >> 16) & 1u);
    return (unsigned short)(r >> 16);
}

struct GemmB {
    const float* A;        // M x K fp32, row stride lda
    const unsigned short* W;  // N x K bf16 bits, K-major
    float* C;              // M x N fp32, row stride ldc
    const float* bias;     // length N or nullptr
};

// C = A @ W^T. BM=BN=128, BK=32, 256 threads (4 waves, each 64x64 = 4x4 frags).
template <bool RELU>
__global__ __launch_bounds__(256) void gemm_bf16(GemmB d0, GemmB d1, int K, int lda,
                                                 int ldc) {
    GemmB d = blockIdx.z ? d1 : d0;
    __shared__ unsigned short As[128 * 40];  // [128 rows][32 k + 8 pad] bf16
    __shared__ unsigned short Ws[128 * 40];
    const int tid = threadIdx.x;
    const int lane = tid & 63, wid = tid >> 6;
    const int wr = wid >> 1, wc = wid & 1;
    const int r16 = lane & 15, ko = lane >> 4;
    const int brow = blockIdx.y * 128;
    const int bcol = blockIdx.x * 128;

    // staging coords: thread t -> row r = t>>1, k-half h = (t&1)*16
    const int sr = tid >> 1;
    const int sh = (tid & 1) * 16;

    f32x4 acc[4][4];
#pragma unroll
    for (int i = 0; i < 4; ++i)
#pragma unroll
        for (int j = 0; j < 4; ++j) acc[i][j] = (f32x4)0.f;

    int aoff[4], boff[4];
#pragma unroll
    for (int i = 0; i < 4; ++i) {
        aoff[i] = (wr * 64 + i * 16 + r16) * 40 + ko * 8;
        boff[i] = (wc * 64 + i * 16 + r16) * 40 + ko * 8;
    }

    for (int k0 = 0; k0 < K; k0 += 32) {
        // stage A (fp32 -> bf16): 16 elems per thread
        {
            const float* src = d.A + (size_t)(brow + sr) * lda + k0 + sh;
            float4 v0 = *(const float4*)(src + 0);
            float4 v1 = *(const float4*)(src + 4);
            float4 v2 = *(const float4*)(src + 8);
            float4 v3 = *(const float4*)(src + 12);
            ushort8v p0, p1;
            p0[0] = f2bf(v0.x); p0[1] = f2bf(v0.y); p0[2] = f2bf(v0.z); p0[3] = f2bf(v0.w);
            p0[4] = f2bf(v1.x); p0[5] = f2bf(v1.y); p0[6] = f2bf(v1.z); p0[7] = f2bf(v1.w);
            p1[0] = f2bf(v2.x); p1[1] = f2bf(v2.y); p1[2] = f2bf(v2.z); p1[3] = f2bf(v2.w);
            p1[4] = f2bf(v3.x); p1[5] = f2bf(v3.y); p1[6] = f2bf(v3.z); p1[7] = f2bf(v3.w);
            *(ushort8v*)&As[sr * 40 + sh] = p0;
            *(ushort8v*)&As[sr * 40 + sh + 8] = p1;
        }
        // stage W (bf16 passthrough): 16 elems per thread
        {
            const unsigned short* src = d.W + (size_t)(bcol + sr) * K + k0 + sh;
            ushort8v w0 = *(const ushort8v*)(src + 0);
            ushort8v w1 = *(const ushort8v*)(src + 8);
            *(ushort8v*)&Ws[sr * 40 + sh] = w0;
            *(ushort8v*)&Ws[sr * 40 + sh + 8] = w1;
        }
        __syncthreads();
        bf16x8 a[4], b[4];
#pragma unroll
        for (int i = 0; i < 4; ++i) a[i] = *(const bf16x8*)&As[aoff[i]];
#pragma unroll
        for (int i = 0; i < 4; ++i) b[i] = *(const bf16x8*)&Ws[boff[i]];
#pragma unroll
        for (int mi = 0; mi < 4; ++mi)
#pragma unroll
            for (int ni = 0; ni < 4; ++ni)
                acc[mi][ni] = __builtin_amdgcn_mfma_f32_16x16x32_bf16(
                    a[mi], b[ni], acc[mi][ni], 0, 0, 0);
        __syncthreads();
    }

    const int crow0 = brow + wr * 64 + (lane >> 4) * 4;
    const int ccol0 = bcol + wc * 64 + r16;
#pragma unroll
    for (int mi = 0; mi < 4; ++mi) {
#pragma unroll
        for (int ni = 0; ni < 4; ++ni) {
            int col = ccol0 + ni * 16;
            float bv = d.bias ? d.bias[col] : 0.f;
#pragma unroll
            for (int j = 0; j < 4; ++j) {
                int row = crow0 + mi * 16 + j;
                float v = acc[mi][ni][j] + bv;
                if (RELU) v = fmaxf(v, 0.f);
                d.C[(size_t)row * ldc + col] = v;
            }
        }
    }
}

// flat fp32 -> bf16 convert, 8 elems/thread
__global__ __launch_bounds__(256) void convert_bf16(const float* in, unsigned short* out) {
    size_t i = ((size_t)blockIdx.x * 256 + threadIdx.x) * 8;
    float4 v0 = *(const float4*)(in + i);
    float4 v1 = *(const float4*)(in + i + 4);
    ushort8v p;
    p[0] = f2bf(v0.x); p[1] = f2bf(v0.y); p[2] = f2bf(v0.z); p[3] = f2bf(v0.w);
    p[4] = f2bf(v1.x); p[5] = f2bf(v1.y); p[6] = f2bf(v1.z); p[7] = f2bf(v1.w);
    *(ushort8v*)(out + i) = p;
}

// W1 [T][K=512][N=512] fp32 -> W1T [T][N][K] bf16
__global__ __launch_bounds__(256) void transpose_w1(const float* W1, unsigned short* W1T) {
    __shared__ float tile[32][33];
    int t = blockIdx.z;
    int n0 = blockIdx.x * 32, k0 = blockIdx.y * 32;
    int tx = threadIdx.x & 31, ty = threadIdx.x >> 5;
#pragma unroll
    for (int j = 0; j < 4; ++j)
        tile[ty + 8 * j][tx] = W1[((size_t)t * 512 + k0 + ty + 8 * j) * 512 + n0 + tx];
    __syncthreads();
#pragma unroll
    for (int j = 0; j < 4; ++j)
        W1T[((size_t)t * 512 + n0 + ty + 8 * j) * 512 + k0 + tx] =
            f2bf(tile[tx][ty + 8 * j]);
}

__global__ __launch_bounds__(256) void build_combined(const float* z, const float* cond,
                                                      float* combined, float* pos) {
    int idx = blockIdx.x * 256 + threadIdx.x;
    int b = idx >> 8, k = idx & 255;
    combined[idx] = (k < LAT) ? z[b * LAT + k] : cond[b * COND + (k - LAT)];
    if (idx < BATCH * 2) pos[idx] = 0.f;
}

__device__ inline float sigmoidf_(float x) { return 1.f / (1.f + expf(-x)); }

__global__ __launch_bounds__(256) void ew_layer0(const float* gh, const float* pos,
                                                 const float* W_ih0, const float* b_ih0,
                                                 const float* b_hh0, float* h) {
    int idx = blockIdx.x * 256 + threadIdx.x;
    int b = idx >> 9, j = idx & 511;
    float px = pos[b * 2 + 0], py = pos[b * 2 + 1];
    float gi_r = px * W_ih0[j * 2 + 0] + py * W_ih0[j * 2 + 1] + b_ih0[j];
    float gi_z = px * W_ih0[(512 + j) * 2 + 0] + py * W_ih0[(512 + j) * 2 + 1] + b_ih0[512 + j];
    float gi_n = px * W_ih0[(1024 + j) * 2 + 0] + py * W_ih0[(1024 + j) * 2 + 1] + b_ih0[1024 + j];
    size_t rb = (size_t)b * H3;
    float hr = gh[rb + j] + b_hh0[j];
    float hz = gh[rb + 512 + j] + b_hh0[512 + j];
    float hn = gh[rb + 1024 + j] + b_hh0[1024 + j];
    float r = sigmoidf_(gi_r + hr);
    float zg = sigmoidf_(gi_z + hz);
    float n = tanhf(gi_n + r * hn);
    float hp = h[rb + j];
    h[rb + j] = (1.f - zg) * n + zg * hp;
}

__global__ __launch_bounds__(256) void ew_gruL(const float* gi, const float* gh,
                                               const float* b_ihl, const float* b_hhl,
                                               float* h, int colOff) {
    int idx = blockIdx.x * 256 + threadIdx.x;
    int b = idx >> 9, j = idx & 511;
    size_t rb = (size_t)b * H3;
    float ir = gi[rb + j] + b_ihl[j];
    float iz = gi[rb + 512 + j] + b_ihl[512 + j];
    float inn = gi[rb + 1024 + j] + b_ihl[1024 + j];
    float hr = gh[rb + j] + b_hhl[j];
    float hz = gh[rb + 512 + j] + b_hhl[512 + j];
    float hn = gh[rb + 1024 + j] + b_hhl[1024 + j];
    float r = sigmoidf_(ir + hr);
    float zg = sigmoidf_(iz + hz);
    float n = tanhf(inn + r * hn);
    float hp = h[rb + colOff + j];
    h[rb + colOff + j] = (1.f - zg) * n + zg * hp;
}

__global__ __launch_bounds__(256) void mlp2_pos(const float* hid, const float* W2t,
                                                const float* b2t, float* pos, float* out,
                                                int t) {
    int b = blockIdx.x * 4 + (threadIdx.x >> 6);
    int lane = threadIdx.x & 63;
    const float* hr = hid + (size_t)b * H;
    float a0 = 0.f, a1 = 0.f;
    for (int k = lane; k < H; k += 64) {
        float x = hr[k];
        a0 += x * W2t[k * 2 + 0];
        a1 += x * W2t[k * 2 + 1];
    }
#pragma unroll
    for (int off = 32; off; off >>= 1) {
        a0 += __shfl_down(a0, off);
        a1 += __shfl_down(a1, off);
    }
    if (lane == 0) {
        float p0 = pos[b * 2 + 0] + a0 + b2t[0];
        float p1 = pos[b * 2 + 1] + a1 + b2t[1];
        pos[b * 2 + 0] = p0;
        pos[b * 2 + 1] = p1;
        out[((size_t)b * T_STEPS + t) * 2 + 0] = p0;
        out[((size_t)b * T_STEPS + t) * 2 + 1] = p1;
    }
}

extern "C" void kernel_launch(void* const* d_in, const int* in_sizes, int n_in,
                              void* d_out, int out_size, void* d_ws, size_t ws_size,
                              hipStream_t stream) {
    const float* z = (const float*)d_in[0];
    const float* cond = (const float*)d_in[1];
    const float* hp_W = (const float*)d_in[2];
    const float* hp_b = (const float*)d_in[3];
    const float* W_ih0 = (const float*)d_in[4];
    const float* W_ihr = (const float*)d_in[5];
    const float* W_hh = (const float*)d_in[6];
    const float* b_ih = (const float*)d_in[7];
    const float* b_hh = (const float*)d_in[8];
    const float* W1 = (const float*)d_in[9];
    const float* b1 = (const float*)d_in[10];
    const float* W2 = (const float*)d_in[11];
    const float* b2 = (const float*)d_in[12];
    float* out = (float*)d_out;

    char* p = (char*)d_ws;
    float* combined = (float*)p; p += (size_t)BATCH * D_IN * 4;
    float* h = (float*)p;        p += (size_t)BATCH * H3 * 4;
    float* gh = (float*)p;       p += (size_t)BATCH * H3 * 4;
    float* gi = (float*)p;       p += (size_t)BATCH * H3 * 4;
    float* hid = (float*)p;      p += (size_t)BATCH * H * 4;
    float* pos = (float*)p;      p += (size_t)BATCH * 2 * 4;
    unsigned short* hpW_bf = (unsigned short*)p;  p += (size_t)H3 * D_IN * 2;
    unsigned short* Whh_bf = (unsigned short*)p;  p += (size_t)L_LAYERS * H3 * H * 2;
    unsigned short* Wihr_bf = (unsigned short*)p; p += (size_t)(L_LAYERS - 1) * H3 * H * 2;
    unsigned short* W1T_bf = (unsigned short*)p;  p += (size_t)T_STEPS * H * H * 2;

    build_combined<<<dim3((BATCH * D_IN) / 256), dim3(256), 0, stream>>>(z, cond, combined, pos);
    convert_bf16<<<dim3((H3 * D_IN) / 2048), dim3(256), 0, stream>>>(hp_W, hpW_bf);
    convert_bf16<<<dim3((L_LAYERS * H3 * H) / 2048), dim3(256), 0, stream>>>(W_hh, Whh_bf);
    convert_bf16<<<dim3(((L_LAYERS - 1) * H3 * H) / 2048), dim3(256), 0, stream>>>(W_ihr, Wihr_bf);
    transpose_w1<<<dim3(16, 16, T_STEPS), dim3(256), 0, stream>>>(W1, W1T_bf);

    {   // h0 init: combined @ hp_W^T + hp_b
        GemmB di{combined, hpW_bf, h, hp_b};
        gemm_bf16<false><<<dim3(H3 / 128, BATCH / 128, 1), dim3(256), 0, stream>>>(
            di, di, D_IN, D_IN, H3);
    }

    dim3 ewGrid((BATCH * H) / 256);
    for (int t = 0; t < T_STEPS; ++t) {
        {   // gh0 = h0 @ W_hh[0]^T
            GemmB g0{h, Whh_bf, gh, nullptr};
            gemm_bf16<false><<<dim3(H3 / 128, BATCH / 128, 1), dim3(256), 0, stream>>>(
                g0, g0, H, H3, H3);
        }
        ew_layer0<<<ewGrid, dim3(256), 0, stream>>>(gh, pos, W_ih0, b_ih, b_hh, h);
        {   // gi1 = h0(t) @ W_ihr[0]^T ; gh1 = h1(t-1) @ W_hh[1]^T
            GemmB g1{h, Wihr_bf, gi, nullptr};
            GemmB g2{h + H, Whh_bf + (size_t)H3 * H, gh, nullptr};
            gemm_bf16<false><<<dim3(H3 / 128, BATCH / 128, 2), dim3(256), 0, stream>>>(
                g1, g2, H, H3, H3);
        }
        ew_gruL<<<ewGrid, dim3(256), 0, stream>>>(gi, gh, b_ih + H3, b_hh + H3, h, H);
        {   // gi2 = h1(t) @ W_ihr[1]^T ; gh2 = h2(t-1) @ W_hh[2]^T
            GemmB g3{h + H, Wihr_bf + (size_t)H3 * H, gi, nullptr};
            GemmB g4{h + 2 * H, Whh_bf + (size_t)2 * H3 * H, gh, nullptr};
            gemm_bf16<false><<<dim3(H3 / 128, BATCH / 128, 2), dim3(256), 0, stream>>>(
                g3, g4, H, H3, H3);
        }
        ew_gruL<<<ewGrid, dim3(256), 0, stream>>>(gi, gh, b_ih + 2 * H3, b_hh + 2 * H3, h, 2 * H);
        {   // hid = relu(h2(t) @ W1T[t]^T + b1[t])
            GemmB g5{h + 2 * H, W1T_bf + (size_t)t * H * H, hid, b1 + (size_t)t * H};
            gemm_bf16<true><<<dim3(H / 128, BATCH / 128, 1), dim3(256), 0, stream>>>(
                g5, g5, H, H3, H);
        }
        mlp2_pos<<<dim3(BATCH / 4), dim3(256), 0, stream>>>(
            hid, W2 + (size_t)t * H * 2, b2 + t * 2, pos, out, t);
    }
}